// Round 4
// baseline (728.902 us; speedup 1.0000x reference)
//
#include <hip/hip_runtime.h>
#include <math.h>

#define N_GRD 4
#define M_SAT 32
#define C_CH  32
#define HK    64
#define WK    64
#define HO    65
#define WO    65
#define SAMPLE_ELEMS (C_CH * HK * WK)

typedef _Float16 h8 __attribute__((ext_vector_type(8)));
typedef float    f4 __attribute__((ext_vector_type(4)));
typedef unsigned int u32;

// ---- ws layout (float units) ----
#define OFF_INV   0
#define OFF_S     64
#define OFF_CANDV 135264              // 64 + 32*4225
#define OFF_CANDI 135776
#define OFF_DOTS  136288
#define OFF_EDGE  136800              // 32*4*129 = 16512 exact edge dots
#define OFF_PART  153312
#define PART_FLOATS 4194304           // 8 slices * 32 m * 4 xs * 4 t * 4 n * 256
#define OFF_G2F   (OFF_PART + PART_FLOATS)
#define G2_HALFS  1736704             // 2cp * 8cq * 64i * 4n * 106js * 4c

// ---------------------------------------------------------------------------
// K0: grd inverse L2 norms (4 blocks).  sat norms come from sat_s2_kernel.
// ---------------------------------------------------------------------------
__global__ __launch_bounds__(256) void norms_kernel(const float* __restrict__ grd,
                                                    float* __restrict__ inv) {
    int b = blockIdx.x;
    const float4* v = reinterpret_cast<const float4*>(grd + (size_t)b * SAMPLE_ELEMS);
    float ss = 0.0f;
    for (int p = threadIdx.x; p < SAMPLE_ELEMS / 4; p += 256) {
        float4 q = v[p];
        ss += q.x * q.x + q.y * q.y + q.z * q.z + q.w * q.w;
    }
    for (int off = 32; off > 0; off >>= 1) ss += __shfl_down(ss, off);
    __shared__ float ls[4];
    int lane = threadIdx.x & 63, w = threadIdx.x >> 6;
    if (lane == 0) ls[w] = ss;
    __syncthreads();
    if (threadIdx.x == 0) {
        float t = ls[0] + ls[1] + ls[2] + ls[3];
        inv[b] = 1.0f / fmaxf(sqrtf(t), 1e-12f);
    }
}

// ---------------------------------------------------------------------------
// K1: per-m summed-area table of s2 (65x65 exclusive SAT) + sat inv-norm
// (total sum == last inclusive prefix entry, free).
// ---------------------------------------------------------------------------
__global__ __launch_bounds__(256) void sat_s2_kernel(const float* __restrict__ sat,
                                                     float* __restrict__ S,
                                                     float* __restrict__ inv) {
    int m = blockIdx.x;
    __shared__ float s2[64][65];
    const float* base = sat + (size_t)m * SAMPLE_ELEMS;
    for (int p = threadIdx.x; p < HK * WK; p += 256) {
        float s = 0.0f;
        for (int c = 0; c < C_CH; ++c) {
            float v = base[c * (HK * WK) + p];
            s += v * v;
        }
        s2[p >> 6][p & 63] = s;
    }
    __syncthreads();
    if (threadIdx.x < 64) {
        int r = threadIdx.x;
        float run = 0.0f;
        for (int w = 0; w < 64; ++w) { run += s2[r][w]; s2[r][w] = run; }
    }
    __syncthreads();
    if (threadIdx.x < 64) {
        int c = threadIdx.x;
        float run = 0.0f;
        for (int h = 0; h < 64; ++h) { run += s2[h][c]; s2[h][c] = run; }
    }
    __syncthreads();
    if (threadIdx.x == 0)
        inv[N_GRD + m] = 1.0f / fmaxf(sqrtf(s2[63][63]), 1e-12f);
    float* Sm = S + (size_t)m * (HO * WO);
    for (int p = threadIdx.x; p < HO * WO; p += 256) {
        int r = p / 65, c = p - r * 65;
        Sm[p] = (r == 0 || c == 0) ? 0.0f : s2[r - 1][c - 1];
    }
}

// ---------------------------------------------------------------------------
// K2: build g2 (fp16 Toeplitz source), layout [cp2][cq8][i64][n4][js106][c4].
// ---------------------------------------------------------------------------
__global__ __launch_bounds__(256) void g2_prep_kernel(const float* __restrict__ grd,
                                                      _Float16* __restrict__ g2) {
    int idx = blockIdx.x * 256 + threadIdx.x;
    if (idx >= G2_HALFS) return;
    int c = idx & 3; int t = idx >> 2;
    int js = t % 106; t /= 106;
    int n = t & 3; t >>= 2;
    int i = t & 63; t >>= 6;
    int cq = t & 7; int cp = t >> 3;
    int j = js - 16 - cp;
    float v = 0.0f;
    if (j >= 0 && j < 64)
        v = grd[(((size_t)n * 32 + (cq * 4 + c)) * 64 + i) * 64 + j];
    g2[idx] = (_Float16)v;
}

// ---------------------------------------------------------------------------
// K3: main MFMA correlation, 64x64 main region only (edges done exactly in
// edge_kernel).  Grid (m=32, xs=4, z=8: h=z&1 qhalf, qt=z>>1 cquarter).
// Per wave: 4 y-tiles (y0 in {0,16,32,48}) x 4 n.
// partial[h][qt][m][xs][t][n][x*16+y] fp32.
// ---------------------------------------------------------------------------
__global__ __launch_bounds__(256, 2) void corr_mfma_kernel(const float* __restrict__ sat,
                                                           const _Float16* __restrict__ g2,
                                                           float* __restrict__ partial) {
    __shared__ __align__(16) char lds[43008 + 28672];
    char* AB = lds;
    char* BB = lds + 43008;

    const int m  = blockIdx.x;
    const int xs = blockIdx.y;            // x0 = 16*xs, all aligned (xoff=0)
    const int z  = blockIdx.z;
    const int h  = z & 1;
    const int qt = z >> 1;
    const int qstage = 16 * xs + 40 * h;

    const int tid  = threadIdx.x;
    const int w    = tid >> 6;
    const int lane = tid & 63;
    const int s    = lane & 15;
    const int u    = lane >> 4;
    const int cp   = s & 1;

    f4 acc[4][4];
#pragma unroll
    for (int t = 0; t < 4; ++t)
#pragma unroll
        for (int n = 0; n < 4; ++n) { acc[t][n][0]=0.f; acc[t][n][1]=0.f; acc[t][n][2]=0.f; acc[t][n][3]=0.f; }

    const int bbase = ((w * 2 + cp) * 4 * 106 + (16 + cp + 40 * h + 2 * u - s)) * 8;
    const int abase0 = s * 336 + u * 16;

    for (int cqi = 0; cqi < 2; ++cqi) {
        const int cq = qt * 2 + cqi;
        __syncthreads();
        // ---- stage A: 128 padded rows x 21 granules (g==20 is stride pad)
        for (int k = 0; k < 11; ++k) {
            int idx = k * 256 + tid;
            if (idx < 2688) {
                int r = idx / 21;
                int g = idx - r * 21;
                int q = qstage + 2 * g;
                h8 hv = {0, 0, 0, 0, 0, 0, 0, 0};
                if (g < 20 && r >= 32 && r < 96 && q >= 32 && q < 96) {
                    const float* sp = sat + (((size_t)(m * 32 + cq * 4)) * 64 + (r - 32)) * 64 + (q - 32);
                    float2 v0 = *(const float2*)(sp);
                    float2 v1 = *(const float2*)(sp + 4096);
                    float2 v2 = *(const float2*)(sp + 8192);
                    float2 v3 = *(const float2*)(sp + 12288);
                    hv[0] = (_Float16)v0.x; hv[1] = (_Float16)v1.x; hv[2] = (_Float16)v2.x; hv[3] = (_Float16)v3.x;
                    hv[4] = (_Float16)v0.y; hv[5] = (_Float16)v1.y; hv[6] = (_Float16)v2.y; hv[7] = (_Float16)v3.y;
                }
                *(h8*)(AB + idx * 16) = hv;
            }
        }
        for (int ii = 0; ii < 16; ++ii) {
            __syncthreads();
            for (int k = 0; k < 7; ++k) {
                int idx = k * 256 + tid;
                if (idx < 1696) {
                    int wi = idx / 424;  int rm  = idx - wi * 424;
                    int cpp = rm / 212;  int rm2 = rm - cpp * 212;
                    int nn = rm2 / 53;   int jg  = rm2 - nn * 53;
                    int iw = wi * 16 + ii;
                    const _Float16* gsrc = g2 + (size_t)((((cpp * 8 + cq) * 64 + iw) * 4 + nn)) * 424 + jg * 8;
                    __builtin_amdgcn_global_load_lds(
                        (const __attribute__((address_space(1))) u32*)(const void*)gsrc,
                        (__attribute__((address_space(3))) u32*)(void*)(BB + k * 4096 + w * 1024),
                        16, 0, 0);
                }
            }
            __syncthreads();
            const int i = w * 16 + ii;
            const char* Ab = AB + abase0 + i * 336;
            const char* Bb = BB + bbase;
#pragma unroll
            for (int qs = 0; qs < 5; ++qs) {
                h8 a[4]; h8 bfr[4];
#pragma unroll
                for (int t = 0; t < 4; ++t) a[t] = *(const h8*)(Ab + qs * 64 + t * 5376);
#pragma unroll
                for (int n = 0; n < 4; ++n) bfr[n] = *(const h8*)(Bb + qs * 64 + n * 848);
#pragma unroll
                for (int t = 0; t < 4; ++t)
#pragma unroll
                    for (int n = 0; n < 4; ++n)
                        acc[t][n] = __builtin_amdgcn_mfma_f32_16x16x32_f16(a[t], bfr[n], acc[t][n], 0, 0, 0);
            }
        }
    }

    // ---- cross-wave (i-quarter) reduce in LDS, then plain stores
    float* red = (float*)lds;
    const int pbase = ((((h * 4 + qt) * 32 + m)) * 4 + xs) * 4096;
#pragma unroll
    for (int pass = 0; pass < 4; ++pass) {
        __syncthreads();
#pragma unroll
        for (int tp = 0; tp < 4; ++tp)
            *(f4*)(red + ((tp * 4 + w) * 64 + lane) * 4) = acc[pass][tp];
        __syncthreads();
        {
            int tp = tid >> 6, ln = tid & 63;
            f4 sum = *(f4*)(red + ((tp * 4 + 0) * 64 + ln) * 4);
            sum = sum + *(f4*)(red + ((tp * 4 + 1) * 64 + ln) * 4);
            sum = sum + *(f4*)(red + ((tp * 4 + 2) * 64 + ln) * 4);
            sum = sum + *(f4*)(red + ((tp * 4 + 3) * 64 + ln) * 4);
            int ss = ln & 15, uu = ln >> 4;
            *(f4*)(partial + pbase + (pass * 4 + tp) * 256 + ss * 16 + uu * 4) = sum;
        }
    }
}

// ---------------------------------------------------------------------------
// K3b: exact fp32 dots for the 129 edge points (y==64 or x==64), all 4 n.
// edge[(m*4+n)*129 + e],  e<65: (y=64,x=e);  e>=65: (y=e-65,x=64).
// ---------------------------------------------------------------------------
__global__ __launch_bounds__(256) void edge_kernel(const float* __restrict__ grd,
                                                   const float* __restrict__ sat,
                                                   float* __restrict__ edge) {
    const int e = blockIdx.x;
    const int m = blockIdx.y;
    int y, x;
    if (e < 65) { y = 64; x = e; } else { y = e - 65; x = 64; }
    const int tid = threadIdx.x, lane = tid & 63, w = tid >> 6;
    const int ilo = max(0, 32 - y), ihi = min(64, 96 - y);
    const int jlo = max(0, 32 - x), jhi = min(64, 96 - x);
    const int j = jlo + lane;
    float a0 = 0.f, a1 = 0.f, a2 = 0.f, a3 = 0.f;
    if (j < jhi) {
        const int scol = x + j - 32;
        const float* sm = sat + (size_t)m * SAMPLE_ELEMS;
        for (int c = 0; c < 32; ++c) {
            const int cbase = c << 12;
            const float* sp = sm + cbase + scol;
            const float* g0 = grd + cbase + j;
            for (int i = ilo + w; i < ihi; i += 4) {
                float sv = sp[(y + i - 32) << 6];
                int go = i << 6;
                a0 = fmaf(sv, g0[go], a0);
                a1 = fmaf(sv, g0[SAMPLE_ELEMS + go], a1);
                a2 = fmaf(sv, g0[2 * SAMPLE_ELEMS + go], a2);
                a3 = fmaf(sv, g0[3 * SAMPLE_ELEMS + go], a3);
            }
        }
    }
    for (int off = 32; off > 0; off >>= 1) {
        a0 += __shfl_down(a0, off); a1 += __shfl_down(a1, off);
        a2 += __shfl_down(a2, off); a3 += __shfl_down(a3, off);
    }
    __shared__ float ls[4][4];
    if (lane == 0) { ls[w][0] = a0; ls[w][1] = a1; ls[w][2] = a2; ls[w][3] = a3; }
    __syncthreads();
    if (tid < 4)
        edge[((size_t)m * 4 + tid) * 129 + e] =
            ls[0][tid] + ls[1][tid] + ls[2][tid] + ls[3][tid];
}

// ---------------------------------------------------------------------------
// K4: reduce partials (+edge) + normalize + top-4 candidates per (m,n).
// ---------------------------------------------------------------------------
__global__ __launch_bounds__(256) void epilogue_kernel(const float* __restrict__ partial,
                                                       const float* __restrict__ edge,
                                                       const float* __restrict__ S,
                                                       const float* __restrict__ inv,
                                                       const int* __restrict__ unc,
                                                       float* __restrict__ candv,
                                                       int* __restrict__ candi) {
    const int b = blockIdx.x;
    const int m = b >> 2, n = b & 3;
    const int tid = threadIdx.x;
    const float uu = (float)unc[0];
    const float sc = inv[n] * inv[N_GRD + m];
    const float isn = inv[N_GRD + m];
    const float* Sm = S + (size_t)m * 4225;
    const float* pb = partial + m * 16384;
    const float* eb = edge + ((size_t)m * 4 + n) * 129;

    float best = -3.4e38f;
    int bidx = 0;
    for (int p = tid; p < 4225; p += 256) {
        int y = p / 65, x = p - y * 65;
        float raw;
        if (y < 64 && x < 64) {
            int so = (x >> 4) * 4096 + ((y >> 4) * 4 + n) * 256 + (x & 15) * 16 + (y & 15);
            raw = 0.0f;
#pragma unroll
            for (int hq = 0; hq < 8; ++hq) raw += pb[hq * 524288 + so];
        } else {
            raw = eb[(y == 64) ? x : (65 + y)];
        }
        float num = raw * sc;
        int r0 = max(0, y - 32), r1 = min(64, y + 32);
        int q0 = max(0, x - 32), q1 = min(64, x + 32);
        float ps = Sm[r1 * 65 + q1] - Sm[r0 * 65 + q1] - Sm[r1 * 65 + q0] + Sm[r0 * 65 + q0];
        float denom = fmaxf(sqrtf(ps) * isn * uu, 1e-12f);
        float v = num / denom;
        if (v > best) { best = v; bidx = p; }
    }
    __shared__ float bv[256]; __shared__ int bi[256];
    __shared__ float cv[256]; __shared__ int ci[256];
    __shared__ int winner;
    bv[tid] = best; bi[tid] = bidx;
    __syncthreads();
    for (int round = 0; round < 4; ++round) {
        cv[tid] = bv[tid]; ci[tid] = bi[tid];
        __syncthreads();
        for (int st = 128; st > 0; st >>= 1) {
            if (tid < st) {
                float ov = cv[tid + st]; int oi = ci[tid + st];
                if (ov > cv[tid] || (ov == cv[tid] && oi < ci[tid])) { cv[tid] = ov; ci[tid] = oi; }
            }
            __syncthreads();
        }
        if (tid == 0) { candv[b * 4 + round] = cv[0]; candi[b * 4 + round] = ci[0]; winner = ci[0]; }
        __syncthreads();
        if (bi[tid] == winner) bv[tid] = -3.4e38f;
        __syncthreads();
    }
}

// ---------------------------------------------------------------------------
// K5a: exact fp32 dot for candidate slot (b,k).  Branch-free valid ranges,
// independent loads -> pipelined.
// ---------------------------------------------------------------------------
__global__ __launch_bounds__(256) void refine_dot_kernel(const float* __restrict__ grd,
                                                         const float* __restrict__ sat,
                                                         const float* __restrict__ candv,
                                                         const int* __restrict__ candi,
                                                         float* __restrict__ dots) {
    const int b = blockIdx.x;
    const int k = blockIdx.y;
    const int m = b >> 2, n = b & 3;
    float v0 = candv[b * 4];
    float thr = v0 - (0.02f * fabsf(v0) + 1e-4f);
    if (k > 0 && candv[b * 4 + k] < thr) {
        if (threadIdx.x == 0) dots[b * 4 + k] = 0.0f;
        return;
    }
    int p = candi[b * 4 + k];
    int y = p / 65, x = p - y * 65;
    const int tid = threadIdx.x, lane = tid & 63, w = tid >> 6;
    const int ilo = max(0, 32 - y), ihi = min(64, 96 - y);
    int xj = x + lane - 32;
    float acc = 0.0f;
    if (xj >= 0 && xj < 64) {
        const float* sm = sat + (size_t)m * SAMPLE_ELEMS;
        const float* gn = grd + (size_t)n * SAMPLE_ELEMS;
        for (int c = 0; c < 32; ++c) {
            const int cbase = c << 12;
            const float* sp = sm + cbase + xj + ((y - 32) << 6);
            const float* gp = gn + cbase + lane;
            for (int i = ilo + w; i < ihi; i += 4)
                acc = fmaf(sp[i << 6], gp[i << 6], acc);
        }
    }
    for (int off = 32; off > 0; off >>= 1) acc += __shfl_down(acc, off);
    __shared__ float ls[4];
    if (lane == 0) ls[w] = acc;
    __syncthreads();
    if (tid == 0) dots[b * 4 + k] = ls[0] + ls[1] + ls[2] + ls[3];
}

// ---------------------------------------------------------------------------
// K5b: pick best refined candidate per (m,n), write outputs.  1 block.
// ---------------------------------------------------------------------------
__global__ __launch_bounds__(128) void refine_pick_kernel(const float* __restrict__ S,
                                                          const float* __restrict__ inv,
                                                          const int* __restrict__ unc,
                                                          const float* __restrict__ candv,
                                                          const int* __restrict__ candi,
                                                          const float* __restrict__ dots,
                                                          float* __restrict__ out) {
    int b = threadIdx.x;
    if (b >= 128) return;
    const int m = b >> 2, n = b & 3;
    const float uu = (float)unc[0];
    const float sc = inv[n] * inv[N_GRD + m];
    const float isn = inv[N_GRD + m];
    const float* Sm = S + (size_t)m * 4225;
    float v0 = candv[b * 4];
    float thr = v0 - (0.02f * fabsf(v0) + 1e-4f);
    float bestv = -3.4e38f; int bestp = 0;
    for (int k = 0; k < 4; ++k) {
        if (k > 0 && candv[b * 4 + k] < thr) break;   // candv sorted desc
        int p = candi[b * 4 + k];
        int y = p / 65, x = p - y * 65;
        int r0 = max(0, y - 32), r1 = min(64, y + 32);
        int q0 = max(0, x - 32), q1 = min(64, x + 32);
        float ps = Sm[r1 * 65 + q1] - Sm[r0 * 65 + q1] - Sm[r1 * 65 + q0] + Sm[r0 * 65 + q0];
        float denom = fmaxf(sqrtf(ps) * isn * uu, 1e-12f);
        float v = dots[b * 4 + k] * sc / denom;
        if (v > bestv || (v == bestv && p < bestp)) { bestv = v; bestp = p; }
    }
    out[b] = bestv;
    int row = bestp / 65, col = bestp - row * 65;
    float pr = -((float)row - 32.5f);
    float pc = (float)col - 32.5f;
    out[128 + b * 2 + 0] = ((pr * 0.2f) * 512.0f) * (1.0f / 128.0f);
    out[128 + b * 2 + 1] = ((pc * 0.2f) * 512.0f) * (1.0f / 128.0f);
}

// ---------------------------------------------------------------------------
extern "C" void kernel_launch(void* const* d_in, const int* in_sizes, int n_in,
                              void* d_out, int out_size, void* d_ws, size_t ws_size,
                              hipStream_t stream) {
    const float* grd = (const float*)d_in[0];
    const float* sat = (const float*)d_in[1];
    const int*   unc = (const int*)d_in[2];
    float* out = (float*)d_out;
    float* ws  = (float*)d_ws;

    float* inv     = ws + OFF_INV;
    float* S       = ws + OFF_S;
    float* candv   = ws + OFF_CANDV;
    int*   candi   = (int*)(ws + OFF_CANDI);
    float* dots    = ws + OFF_DOTS;
    float* edge    = ws + OFF_EDGE;
    float* partial = ws + OFF_PART;
    _Float16* g2   = (_Float16*)(ws + OFF_G2F);   // ~21 MB total ws use

    norms_kernel<<<N_GRD, 256, 0, stream>>>(grd, inv);
    sat_s2_kernel<<<M_SAT, 256, 0, stream>>>(sat, S, inv);
    g2_prep_kernel<<<(G2_HALFS + 255) / 256, 256, 0, stream>>>(grd, g2);
    corr_mfma_kernel<<<dim3(M_SAT, 4, 8), 256, 0, stream>>>(sat, g2, partial);
    edge_kernel<<<dim3(129, M_SAT), 256, 0, stream>>>(grd, sat, edge);
    epilogue_kernel<<<M_SAT * N_GRD, 256, 0, stream>>>(partial, edge, S, inv, unc, candv, candi);
    refine_dot_kernel<<<dim3(128, 4), 256, 0, stream>>>(grd, sat, candv, candi, dots);
    refine_pick_kernel<<<1, 128, 0, stream>>>(S, inv, unc, candv, candi, dots, out);
}

// Round 5
// 510.267 us; speedup vs baseline: 1.4285x; 1.4285x over previous
//
#include <hip/hip_runtime.h>
#include <math.h>

#define N_GRD 4
#define M_SAT 32
#define C_CH  32
#define HK    64
#define WK    64
#define HO    65
#define WO    65
#define SAMPLE_ELEMS (C_CH * HK * WK)

typedef _Float16 h8 __attribute__((ext_vector_type(8)));
typedef float    f4 __attribute__((ext_vector_type(4)));
typedef unsigned int u32;

// ---- ws layout (float units) ----
#define OFF_INV    0
#define OFF_S      64
#define OFF_CANDV  135264             // 64 + 32*4225
#define OFF_CANDI  135776
#define OFF_DOTS   136288
#define OFF_COLP   136800             // 8 chunks * 32 m * (4n*65y) = 66560
#define OFF_CORNER 203360             // 128
#define OFF_PART   203488
#define PART_FLOATS 5242880           // 8 slices * 32 m * 4 xs * 5 t * 4 n * 256
#define OFF_G2F    (OFF_PART + PART_FLOATS)
#define G2_HALFS   1736704            // 2cp * 8cq * 64i * 4n * 106js * 4c

// ---------------------------------------------------------------------------
// K0: grd inverse L2 norms (4 blocks).  sat norms come from sat_s2_kernel.
// ---------------------------------------------------------------------------
__global__ __launch_bounds__(256) void norms_kernel(const float* __restrict__ grd,
                                                    float* __restrict__ inv) {
    int b = blockIdx.x;
    const float4* v = reinterpret_cast<const float4*>(grd + (size_t)b * SAMPLE_ELEMS);
    float ss = 0.0f;
    for (int p = threadIdx.x; p < SAMPLE_ELEMS / 4; p += 256) {
        float4 q = v[p];
        ss += q.x * q.x + q.y * q.y + q.z * q.z + q.w * q.w;
    }
    for (int off = 32; off > 0; off >>= 1) ss += __shfl_down(ss, off);
    __shared__ float ls[4];
    int lane = threadIdx.x & 63, w = threadIdx.x >> 6;
    if (lane == 0) ls[w] = ss;
    __syncthreads();
    if (threadIdx.x == 0) {
        float t = ls[0] + ls[1] + ls[2] + ls[3];
        inv[b] = 1.0f / fmaxf(sqrtf(t), 1e-12f);
    }
}

// ---------------------------------------------------------------------------
// K1: per-m summed-area table of s2 (65x65 exclusive SAT) + sat inv-norm.
// ---------------------------------------------------------------------------
__global__ __launch_bounds__(256) void sat_s2_kernel(const float* __restrict__ sat,
                                                     float* __restrict__ S,
                                                     float* __restrict__ inv) {
    int m = blockIdx.x;
    __shared__ float s2[64][65];
    const float* base = sat + (size_t)m * SAMPLE_ELEMS;
    for (int p = threadIdx.x; p < HK * WK; p += 256) {
        float s = 0.0f;
        for (int c = 0; c < C_CH; ++c) {
            float v = base[c * (HK * WK) + p];
            s += v * v;
        }
        s2[p >> 6][p & 63] = s;
    }
    __syncthreads();
    if (threadIdx.x < 64) {
        int r = threadIdx.x;
        float run = 0.0f;
        for (int w = 0; w < 64; ++w) { run += s2[r][w]; s2[r][w] = run; }
    }
    __syncthreads();
    if (threadIdx.x < 64) {
        int c = threadIdx.x;
        float run = 0.0f;
        for (int h = 0; h < 64; ++h) { run += s2[h][c]; s2[h][c] = run; }
    }
    __syncthreads();
    if (threadIdx.x == 0)
        inv[N_GRD + m] = 1.0f / fmaxf(sqrtf(s2[63][63]), 1e-12f);
    float* Sm = S + (size_t)m * (HO * WO);
    for (int p = threadIdx.x; p < HO * WO; p += 256) {
        int r = p / 65, c = p - r * 65;
        Sm[p] = (r == 0 || c == 0) ? 0.0f : s2[r - 1][c - 1];
    }
}

// ---------------------------------------------------------------------------
// K2: build g2 (fp16 Toeplitz source), layout [cp2][cq8][i64][n4][js106][c4].
// ---------------------------------------------------------------------------
__global__ __launch_bounds__(256) void g2_prep_kernel(const float* __restrict__ grd,
                                                      _Float16* __restrict__ g2) {
    int idx = blockIdx.x * 256 + threadIdx.x;
    if (idx >= G2_HALFS) return;
    int c = idx & 3; int t = idx >> 2;
    int js = t % 106; t /= 106;
    int n = t & 3; t >>= 2;
    int i = t & 63; t >>= 6;
    int cq = t & 7; int cp = t >> 3;
    int j = js - 16 - cp;
    float v = 0.0f;
    if (j >= 0 && j < 64)
        v = grd[(((size_t)n * 32 + (cq * 4 + c)) * 64 + i) * 64 + j];
    g2[idx] = (_Float16)v;
}

// ---------------------------------------------------------------------------
// K3: main MFMA correlation.  Grid (m=32, xs=4, z=8).  NOW 5 y-tiles: t=4
// covers y=64 (row 0 of the tile; rows 1..15 read in-LDS garbage and are
// discarded — MFMA rows are independent).  A staging unchanged.
// partial[slice][m][xs][t5][n][x*16+y] fp32.
// ---------------------------------------------------------------------------
__global__ __launch_bounds__(256, 2) void corr_mfma_kernel(const float* __restrict__ sat,
                                                           const _Float16* __restrict__ g2,
                                                           float* __restrict__ partial) {
    __shared__ __align__(16) char lds[43008 + 28672];
    char* AB = lds;
    char* BB = lds + 43008;

    const int m  = blockIdx.x;
    const int xs = blockIdx.y;
    const int z  = blockIdx.z;
    const int h  = z & 1;
    const int qt = z >> 1;
    const int qstage = 16 * xs + 40 * h;

    const int tid  = threadIdx.x;
    const int w    = tid >> 6;
    const int lane = tid & 63;
    const int s    = lane & 15;
    const int u    = lane >> 4;
    const int cp   = s & 1;

    f4 acc[5][4];
#pragma unroll
    for (int t = 0; t < 5; ++t)
#pragma unroll
        for (int n = 0; n < 4; ++n) { acc[t][n][0]=0.f; acc[t][n][1]=0.f; acc[t][n][2]=0.f; acc[t][n][3]=0.f; }

    const int bbase = ((w * 2 + cp) * 4 * 106 + (16 + cp + 40 * h + 2 * u - s)) * 8;
    const int abase0 = s * 336 + u * 16;

    for (int cqi = 0; cqi < 2; ++cqi) {
        const int cq = qt * 2 + cqi;
        __syncthreads();
        // ---- stage A: 128 padded rows x 21 granules (g==20 is stride pad)
        for (int k = 0; k < 11; ++k) {
            int idx = k * 256 + tid;
            if (idx < 2688) {
                int r = idx / 21;
                int g = idx - r * 21;
                int q = qstage + 2 * g;
                h8 hv = {0, 0, 0, 0, 0, 0, 0, 0};
                if (g < 20 && r >= 32 && r < 96 && q >= 32 && q < 96) {
                    const float* sp = sat + (((size_t)(m * 32 + cq * 4)) * 64 + (r - 32)) * 64 + (q - 32);
                    float2 v0 = *(const float2*)(sp);
                    float2 v1 = *(const float2*)(sp + 4096);
                    float2 v2 = *(const float2*)(sp + 8192);
                    float2 v3 = *(const float2*)(sp + 12288);
                    hv[0] = (_Float16)v0.x; hv[1] = (_Float16)v1.x; hv[2] = (_Float16)v2.x; hv[3] = (_Float16)v3.x;
                    hv[4] = (_Float16)v0.y; hv[5] = (_Float16)v1.y; hv[6] = (_Float16)v2.y; hv[7] = (_Float16)v3.y;
                }
                *(h8*)(AB + idx * 16) = hv;
            }
        }
        for (int ii = 0; ii < 16; ++ii) {
            __syncthreads();
            for (int k = 0; k < 7; ++k) {
                int idx = k * 256 + tid;
                if (idx < 1696) {
                    int wi = idx / 424;  int rm  = idx - wi * 424;
                    int cpp = rm / 212;  int rm2 = rm - cpp * 212;
                    int nn = rm2 / 53;   int jg  = rm2 - nn * 53;
                    int iw = wi * 16 + ii;
                    const _Float16* gsrc = g2 + (size_t)((((cpp * 8 + cq) * 64 + iw) * 4 + nn)) * 424 + jg * 8;
                    __builtin_amdgcn_global_load_lds(
                        (const __attribute__((address_space(1))) u32*)(const void*)gsrc,
                        (__attribute__((address_space(3))) u32*)(void*)(BB + k * 4096 + w * 1024),
                        16, 0, 0);
                }
            }
            __syncthreads();
            const int i = w * 16 + ii;
            const char* Ab = AB + abase0 + i * 336;
            const char* Bb = BB + bbase;
#pragma unroll
            for (int qs = 0; qs < 5; ++qs) {
                h8 a[5]; h8 bfr[4];
#pragma unroll
                for (int t = 0; t < 5; ++t) a[t] = *(const h8*)(Ab + qs * 64 + t * 5376);
#pragma unroll
                for (int n = 0; n < 4; ++n) bfr[n] = *(const h8*)(Bb + qs * 64 + n * 848);
#pragma unroll
                for (int t = 0; t < 5; ++t)
#pragma unroll
                    for (int n = 0; n < 4; ++n)
                        acc[t][n] = __builtin_amdgcn_mfma_f32_16x16x32_f16(a[t], bfr[n], acc[t][n], 0, 0, 0);
            }
        }
    }

    // ---- cross-wave (i-quarter) reduce in LDS, then plain stores
    float* red = (float*)lds;
    const int pbase = ((((h * 4 + qt) * 32 + m)) * 4 + xs) * 5120;
#pragma unroll
    for (int t = 0; t < 5; ++t) {
        __syncthreads();
#pragma unroll
        for (int nn = 0; nn < 4; ++nn)
            *(f4*)(red + ((nn * 4 + w) * 64 + lane) * 4) = acc[t][nn];
        __syncthreads();
        {
            int nn = tid >> 6, ln = tid & 63;
            f4 sum = *(f4*)(red + ((nn * 4 + 0) * 64 + ln) * 4);
            sum = sum + *(f4*)(red + ((nn * 4 + 1) * 64 + ln) * 4);
            sum = sum + *(f4*)(red + ((nn * 4 + 2) * 64 + ln) * 4);
            sum = sum + *(f4*)(red + ((nn * 4 + 3) * 64 + ln) * 4);
            int ss = ln & 15, uu = ln >> 4;
            *(f4*)(partial + pbase + (t * 4 + nn) * 256 + ss * 16 + uu * 4) = sum;
        }
    }
}

// ---------------------------------------------------------------------------
// K3b: x=64 column, y in [0,64), exact fp32.  Grid (q=8 c-chunks, m=32).
// Wave w handles c = 4q+w; lane = y.  sat right-half transposed into LDS
// (stride 65 -> conflict-free), grd staged 8 i-deep per barrier.
// colp[(q*32+m)*260 + n*65 + y] partial over the 4 c of this block.
// ---------------------------------------------------------------------------
__global__ __launch_bounds__(256) void col_edge_kernel(const float* __restrict__ grd,
                                                       const float* __restrict__ sat,
                                                       float* __restrict__ colp) {
    const int q = blockIdx.x, m = blockIdx.y;
    __shared__ float strans[4 * 32 * 65];              // [c][j][r]
    __shared__ __align__(16) float gbuf[8 * 4 * 32 * 4]; // [ib][cc][j][n]
    __shared__ float red[4 * 64 * 4];
    const int tid = threadIdx.x, lane = tid & 63, w = tid >> 6;
    const int cglob = q * 4 + w;

    {   // stage strans for this wave's c (coalesced 32-float runs)
        const float* sp = sat + ((size_t)m * 32 + cglob) * 4096 + 32;
        int jj = lane & 31, r2 = lane >> 5;
        for (int it = 0; it < 32; ++it) {
            int r = it * 2 + r2;
            strans[(w * 32 + jj) * 65 + r] = sp[r * 64 + jj];
        }
    }
    __syncthreads();

    f4 acc = {0.f, 0.f, 0.f, 0.f};
    const int y = lane;
    for (int i0 = 0; i0 < 64; i0 += 8) {
        __syncthreads();
        for (int rep = 0; rep < 16; ++rep) {
            int e = rep * 256 + tid;               // 4096 elements
            int j = e & 31;
            int t2 = e >> 5;                       // 128 combos
            int ib = t2 >> 4;
            int nn = (t2 >> 2) & 3;
            int cc = t2 & 3;
            gbuf[(((ib * 4) + cc) * 32 + j) * 4 + nn] =
                grd[(((size_t)nn * 32 + q * 4 + cc) * 64 + (i0 + ib)) * 64 + j];
        }
        __syncthreads();
        for (int ib = 0; ib < 8; ++ib) {
            int i = i0 + ib;
            int r = y + i - 32;
            bool ok = (r >= 0) && (r < 64);
            int rc = ok ? r : 0;
            const float* sb = strans + (w * 32) * 65 + rc;
            const float* gb = gbuf + ((ib * 4 + w) * 32) * 4;
#pragma unroll 8
            for (int j = 0; j < 32; ++j) {
                float sv = sb[j * 65];
                if (!ok) sv = 0.0f;
                f4 gv = *(const f4*)(gb + j * 4);
                acc[0] = fmaf(gv[0], sv, acc[0]);
                acc[1] = fmaf(gv[1], sv, acc[1]);
                acc[2] = fmaf(gv[2], sv, acc[2]);
                acc[3] = fmaf(gv[3], sv, acc[3]);
            }
        }
    }
    __syncthreads();
    *(f4*)&red[(w * 64 + y) * 4] = acc;
    __syncthreads();
    if (tid < 64) {
        f4 s0 = *(f4*)&red[(0 * 64 + tid) * 4];
        f4 s1 = *(f4*)&red[(1 * 64 + tid) * 4];
        f4 s2 = *(f4*)&red[(2 * 64 + tid) * 4];
        f4 s3 = *(f4*)&red[(3 * 64 + tid) * 4];
        f4 s = (s0 + s1) + (s2 + s3);
        float* dst = colp + ((size_t)q * 32 + m) * 260;
        for (int n = 0; n < 4; ++n) dst[n * 65 + tid] = s[n];
    }
}

// ---------------------------------------------------------------------------
// K3c: corner (y=64,x=64) exact fp32.  32 blocks.
// corner[m*4+n] = sum_{c,i<32,j<32} g[n,c,i,j]*sat[m,c,32+i,32+j]
// ---------------------------------------------------------------------------
__global__ __launch_bounds__(256) void corner_kernel(const float* __restrict__ grd,
                                                     const float* __restrict__ sat,
                                                     float* __restrict__ corner) {
    const int m = blockIdx.x;
    const int tid = threadIdx.x;
    const int cc = tid >> 3, w8 = tid & 7;
    f4 acc = {0.f, 0.f, 0.f, 0.f};
    const float* sp = sat + ((size_t)m * 32 + cc) * 4096;
    const float* g0 = grd + (size_t)cc * 4096;
    for (int i = w8; i < 32; i += 8) {
        const float* srow = sp + (32 + i) * 64 + 32;
        const float* grow = g0 + i * 64;
#pragma unroll
        for (int j4 = 0; j4 < 8; ++j4) {
            f4 s4 = *(const f4*)(srow + j4 * 4);
#pragma unroll
            for (int n = 0; n < 4; ++n) {
                f4 g4 = *(const f4*)(grow + (size_t)n * SAMPLE_ELEMS + j4 * 4);
                acc[n] += s4[0]*g4[0] + s4[1]*g4[1] + s4[2]*g4[2] + s4[3]*g4[3];
            }
        }
    }
    __shared__ float red[256 * 4];
    *(f4*)&red[tid * 4] = acc;
    __syncthreads();
    for (int s = 128; s > 0; s >>= 1) {
        if (tid < s) {
            f4 a = *(f4*)&red[tid * 4];
            f4 b = *(f4*)&red[(tid + s) * 4];
            *(f4*)&red[tid * 4] = a + b;
        }
        __syncthreads();
    }
    if (tid < 4) corner[m * 4 + tid] = red[tid];
}

// ---------------------------------------------------------------------------
// K4: reduce partials (+col/corner) + normalize + top-4 candidates per (m,n).
// ---------------------------------------------------------------------------
__global__ __launch_bounds__(256) void epilogue_kernel(const float* __restrict__ partial,
                                                       const float* __restrict__ colp,
                                                       const float* __restrict__ corner,
                                                       const float* __restrict__ S,
                                                       const float* __restrict__ inv,
                                                       const int* __restrict__ unc,
                                                       float* __restrict__ candv,
                                                       int* __restrict__ candi) {
    const int b = blockIdx.x;
    const int m = b >> 2, n = b & 3;
    const int tid = threadIdx.x;
    const float uu = (float)unc[0];
    const float sc = inv[n] * inv[N_GRD + m];
    const float isn = inv[N_GRD + m];
    const float* Sm = S + (size_t)m * 4225;
    const float* pb = partial + m * 20480;

    float best = -3.4e38f;
    int bidx = 0;
    for (int p = tid; p < 4225; p += 256) {
        int y = p / 65, x = p - y * 65;
        float raw;
        if (x < 64) {
            int t = (y == 64) ? 4 : (y >> 4);
            int row = (y == 64) ? 0 : (y & 15);
            int so = (x >> 4) * 5120 + (t * 4 + n) * 256 + (x & 15) * 16 + row;
            raw = 0.0f;
#pragma unroll
            for (int hq = 0; hq < 8; ++hq) raw += pb[hq * 655360 + so];
        } else if (y < 64) {
            raw = 0.0f;
#pragma unroll
            for (int q = 0; q < 8; ++q) raw += colp[((size_t)q * 32 + m) * 260 + n * 65 + y];
        } else {
            raw = corner[m * 4 + n];
        }
        float num = raw * sc;
        int r0 = max(0, y - 32), r1 = min(64, y + 32);
        int q0 = max(0, x - 32), q1 = min(64, x + 32);
        float ps = Sm[r1 * 65 + q1] - Sm[r0 * 65 + q1] - Sm[r1 * 65 + q0] + Sm[r0 * 65 + q0];
        float denom = fmaxf(sqrtf(ps) * isn * uu, 1e-12f);
        float v = num / denom;
        if (v > best) { best = v; bidx = p; }
    }
    __shared__ float bv[256]; __shared__ int bi[256];
    __shared__ float cv[256]; __shared__ int ci[256];
    __shared__ int winner;
    bv[tid] = best; bi[tid] = bidx;
    __syncthreads();
    for (int round = 0; round < 4; ++round) {
        cv[tid] = bv[tid]; ci[tid] = bi[tid];
        __syncthreads();
        for (int st = 128; st > 0; st >>= 1) {
            if (tid < st) {
                float ov = cv[tid + st]; int oi = ci[tid + st];
                if (ov > cv[tid] || (ov == cv[tid] && oi < ci[tid])) { cv[tid] = ov; ci[tid] = oi; }
            }
            __syncthreads();
        }
        if (tid == 0) { candv[b * 4 + round] = cv[0]; candi[b * 4 + round] = ci[0]; winner = ci[0]; }
        __syncthreads();
        if (bi[tid] == winner) bv[tid] = -3.4e38f;
        __syncthreads();
    }
}

// ---------------------------------------------------------------------------
// K5a: exact fp32 dot for candidate slot (b,k).
// ---------------------------------------------------------------------------
__global__ __launch_bounds__(256) void refine_dot_kernel(const float* __restrict__ grd,
                                                         const float* __restrict__ sat,
                                                         const float* __restrict__ candv,
                                                         const int* __restrict__ candi,
                                                         float* __restrict__ dots) {
    const int b = blockIdx.x;
    const int k = blockIdx.y;
    const int m = b >> 2, n = b & 3;
    float v0 = candv[b * 4];
    float thr = v0 - (0.02f * fabsf(v0) + 1e-4f);
    if (k > 0 && candv[b * 4 + k] < thr) {
        if (threadIdx.x == 0) dots[b * 4 + k] = 0.0f;
        return;
    }
    int p = candi[b * 4 + k];
    int y = p / 65, x = p - y * 65;
    const int tid = threadIdx.x, lane = tid & 63, w = tid >> 6;
    const int ilo = max(0, 32 - y), ihi = min(64, 96 - y);
    int xj = x + lane - 32;
    float acc = 0.0f;
    if (xj >= 0 && xj < 64) {
        const float* sm = sat + (size_t)m * SAMPLE_ELEMS;
        const float* gn = grd + (size_t)n * SAMPLE_ELEMS;
        for (int c = 0; c < 32; ++c) {
            const int cbase = c << 12;
            const float* sp = sm + cbase + xj + ((y - 32) << 6);
            const float* gp = gn + cbase + lane;
            for (int i = ilo + w; i < ihi; i += 4)
                acc = fmaf(sp[i << 6], gp[i << 6], acc);
        }
    }
    for (int off = 32; off > 0; off >>= 1) acc += __shfl_down(acc, off);
    __shared__ float ls[4];
    if (lane == 0) ls[w] = acc;
    __syncthreads();
    if (tid == 0) dots[b * 4 + k] = ls[0] + ls[1] + ls[2] + ls[3];
}

// ---------------------------------------------------------------------------
// K5b: pick best refined candidate per (m,n), write outputs.  1 block.
// ---------------------------------------------------------------------------
__global__ __launch_bounds__(128) void refine_pick_kernel(const float* __restrict__ S,
                                                          const float* __restrict__ inv,
                                                          const int* __restrict__ unc,
                                                          const float* __restrict__ candv,
                                                          const int* __restrict__ candi,
                                                          const float* __restrict__ dots,
                                                          float* __restrict__ out) {
    int b = threadIdx.x;
    if (b >= 128) return;
    const int m = b >> 2, n = b & 3;
    const float uu = (float)unc[0];
    const float sc = inv[n] * inv[N_GRD + m];
    const float isn = inv[N_GRD + m];
    const float* Sm = S + (size_t)m * 4225;
    float v0 = candv[b * 4];
    float thr = v0 - (0.02f * fabsf(v0) + 1e-4f);
    float bestv = -3.4e38f; int bestp = 0;
    for (int k = 0; k < 4; ++k) {
        if (k > 0 && candv[b * 4 + k] < thr) break;
        int p = candi[b * 4 + k];
        int y = p / 65, x = p - y * 65;
        int r0 = max(0, y - 32), r1 = min(64, y + 32);
        int q0 = max(0, x - 32), q1 = min(64, x + 32);
        float ps = Sm[r1 * 65 + q1] - Sm[r0 * 65 + q1] - Sm[r1 * 65 + q0] + Sm[r0 * 65 + q0];
        float denom = fmaxf(sqrtf(ps) * isn * uu, 1e-12f);
        float v = dots[b * 4 + k] * sc / denom;
        if (v > bestv || (v == bestv && p < bestp)) { bestv = v; bestp = p; }
    }
    out[b] = bestv;
    int row = bestp / 65, col = bestp - row * 65;
    float pr = -((float)row - 32.5f);
    float pc = (float)col - 32.5f;
    out[128 + b * 2 + 0] = ((pr * 0.2f) * 512.0f) * (1.0f / 128.0f);
    out[128 + b * 2 + 1] = ((pc * 0.2f) * 512.0f) * (1.0f / 128.0f);
}

// ---------------------------------------------------------------------------
extern "C" void kernel_launch(void* const* d_in, const int* in_sizes, int n_in,
                              void* d_out, int out_size, void* d_ws, size_t ws_size,
                              hipStream_t stream) {
    const float* grd = (const float*)d_in[0];
    const float* sat = (const float*)d_in[1];
    const int*   unc = (const int*)d_in[2];
    float* out = (float*)d_out;
    float* ws  = (float*)d_ws;

    float* inv     = ws + OFF_INV;
    float* S       = ws + OFF_S;
    float* candv   = ws + OFF_CANDV;
    int*   candi   = (int*)(ws + OFF_CANDI);
    float* dots    = ws + OFF_DOTS;
    float* colp    = ws + OFF_COLP;
    float* corner  = ws + OFF_CORNER;
    float* partial = ws + OFF_PART;
    _Float16* g2   = (_Float16*)(ws + OFF_G2F);   // ~25.3 MB total ws use

    norms_kernel<<<N_GRD, 256, 0, stream>>>(grd, inv);
    sat_s2_kernel<<<M_SAT, 256, 0, stream>>>(sat, S, inv);
    g2_prep_kernel<<<(G2_HALFS + 255) / 256, 256, 0, stream>>>(grd, g2);
    corr_mfma_kernel<<<dim3(M_SAT, 4, 8), 256, 0, stream>>>(sat, g2, partial);
    col_edge_kernel<<<dim3(8, M_SAT), 256, 0, stream>>>(grd, sat, colp);
    corner_kernel<<<M_SAT, 256, 0, stream>>>(grd, sat, corner);
    epilogue_kernel<<<M_SAT * N_GRD, 256, 0, stream>>>(partial, colp, corner, S, inv, unc, candv, candi);
    refine_dot_kernel<<<dim3(128, 4), 256, 0, stream>>>(grd, sat, candv, candi, dots);
    refine_pick_kernel<<<1, 128, 0, stream>>>(S, inv, unc, candv, candi, dots, out);
}